// Round 1
// baseline (285.376 us; speedup 1.0000x reference)
//
#include <hip/hip_runtime.h>
#include <math.h>

#define NB 16
#define NN 1024
#define ND 320
#define NL 256
#define NH 256
#define NK 5

// ---------------- KNN: per-thread top-5 scan over 1024 candidates ----------
__global__ __launch_bounds__(256) void knn_kernel(const float* __restrict__ centers,
                                                  int* __restrict__ idx_i,
                                                  float* __restrict__ idx_f) {
    __shared__ float cx[NN], cy[NN], cz[NN];
    int b = blockIdx.y;
    const float* cb = centers + (size_t)b * NN * 3;
    for (int t = threadIdx.x; t < NN; t += 256) {
        cx[t] = cb[t * 3 + 0];
        cy[t] = cb[t * 3 + 1];
        cz[t] = cb[t * 3 + 2];
    }
    __syncthreads();
    int i = blockIdx.x * 256 + threadIdx.x;
    float px = cx[i], py = cy[i], pz = cz[i];
    float bd0 = INFINITY, bd1 = INFINITY, bd2 = INFINITY, bd3 = INFINITY, bd4 = INFINITY;
    int bi0 = -1, bi1 = -1, bi2 = -1, bi3 = -1, bi4 = -1;
    for (int j = 0; j < NN; ++j) {
        float dx = px - cx[j], dy = py - cy[j], dz = pz - cz[j];
        float d = dx * dx + dy * dy + dz * dz;
        // strict < everywhere: matches top_k stable tie-break (earlier index wins)
        if ((j != i) && (d < bd4)) {
            if (d < bd3) {
                bd4 = bd3; bi4 = bi3;
                if (d < bd2) {
                    bd3 = bd2; bi3 = bi2;
                    if (d < bd1) {
                        bd2 = bd1; bi2 = bi1;
                        if (d < bd0) {
                            bd1 = bd0; bi1 = bi0; bd0 = d; bi0 = j;
                        } else { bd1 = d; bi1 = j; }
                    } else { bd2 = d; bi2 = j; }
                } else { bd3 = d; bi3 = j; }
            } else { bd4 = d; bi4 = j; }
        }
    }
    size_t base = ((size_t)b * NN + i) * NK;
    idx_i[base + 0] = bi0; idx_i[base + 1] = bi1; idx_i[base + 2] = bi2;
    idx_i[base + 3] = bi3; idx_i[base + 4] = bi4;
    idx_f[base + 0] = (float)bi0; idx_f[base + 1] = (float)bi1; idx_f[base + 2] = (float)bi2;
    idx_f[base + 3] = (float)bi3; idx_f[base + 4] = (float)bi4;
}

// ---------------- language projection: LP[b][h] = b1[h] + lang[b] @ W1[646:902] ----
__global__ __launch_bounds__(256) void langproj_kernel(const float* __restrict__ lang,
                                                       const float* __restrict__ W1,
                                                       const float* __restrict__ b1,
                                                       float* __restrict__ LP) {
    int b = blockIdx.x;
    int h = threadIdx.x;
    float acc = b1[h];
    const float* lb = lang + (size_t)b * NL;
    for (int l = 0; l < NL; ++l)
        acc = fmaf(lb[l], W1[(size_t)(646 + l) * NH + h], acc);
    LP[(size_t)b * NH + h] = acc;
}

// ---------------- P = feats[16384x320] @ W1cols -> [16384 x 512] ----------
// P[m][0:256]   = feat[m] @ W1[0:320]    (projF)
// P[m][256:512] = feat[m] @ W1[320:640]  (projN)
__global__ __launch_bounds__(256) void proj_gemm_kernel(const float* __restrict__ A,
                                                        const float* __restrict__ W1,
                                                        float* __restrict__ P) {
    __shared__ float As[32][68];  // [k][m], padded: row base 272B -> 16B aligned
    __shared__ float Bs[32][68];  // [k][n]
    int m0 = blockIdx.x * 64;
    int n0 = blockIdx.y * 64;
    int rowbase = (n0 < 256) ? 0 : 320;
    int colbase = n0 & 255;
    int t = threadIdx.x;
    int tx = t & 15, ty = t >> 4;
    float acc[4][4] = {{0.f}};
    for (int k0 = 0; k0 < ND; k0 += 32) {
#pragma unroll
        for (int it = 0; it < 8; ++it) {
            int li = it * 256 + t;
            int r = li >> 5, c = li & 31;
            As[c][r] = A[(size_t)(m0 + r) * ND + k0 + c];
        }
#pragma unroll
        for (int it = 0; it < 8; ++it) {
            int li = it * 256 + t;
            int r = li >> 6, c = li & 63;
            Bs[r][c] = W1[(size_t)(rowbase + k0 + r) * NH + colbase + c];
        }
        __syncthreads();
#pragma unroll
        for (int kk = 0; kk < 32; ++kk) {
            float4 a = *(const float4*)&As[kk][ty * 4];
            float4 bv = *(const float4*)&Bs[kk][tx * 4];
            float av[4] = {a.x, a.y, a.z, a.w};
            float bb[4] = {bv.x, bv.y, bv.z, bv.w};
#pragma unroll
            for (int i2 = 0; i2 < 4; ++i2)
#pragma unroll
                for (int j2 = 0; j2 < 4; ++j2)
                    acc[i2][j2] = fmaf(av[i2], bb[j2], acc[i2][j2]);
        }
        __syncthreads();
    }
#pragma unroll
    for (int i2 = 0; i2 < 4; ++i2) {
        float4 o = make_float4(acc[i2][0], acc[i2][1], acc[i2][2], acc[i2][3]);
        *(float4*)&P[(size_t)(m0 + ty * 4 + i2) * 512 + n0 + tx * 4] = o;
    }
}

// ---------------- score + softmax + context + residual -------------------
// one wave (64 lanes) per (b, i); 4 waves per block
__global__ __launch_bounds__(256) void score_kernel(const float* __restrict__ feats,
                                                    const float* __restrict__ centers,
                                                    const float* __restrict__ sizes,
                                                    const float* __restrict__ P,
                                                    const float* __restrict__ LP,
                                                    const float* __restrict__ W1,
                                                    const float* __restrict__ W2,
                                                    const float* __restrict__ b2,
                                                    const int* __restrict__ idx,
                                                    float* __restrict__ enhanced,
                                                    float* __restrict__ weights) {
    int wave = threadIdx.x >> 6;
    int lane = threadIdx.x & 63;
    int row = blockIdx.x * 4 + wave;     // b*NN + i
    int b = row >> 10;

    const float4* Pv = (const float4*)P;
    float4 pf = Pv[(size_t)row * 128 + lane];            // projF[i], 4 h-dims per lane
    float4 lp = ((const float4*)LP)[(size_t)b * 64 + lane];
    float4 base = make_float4(pf.x + lp.x, pf.y + lp.y, pf.z + lp.z, pf.w + lp.w);
    float4 w2v = ((const float4*)W2)[lane];
    float b2v = b2[0];
    float4 rw0 = *(const float4*)&W1[(size_t)(640 + 0) * NH + lane * 4];
    float4 rw1 = *(const float4*)&W1[(size_t)(640 + 1) * NH + lane * 4];
    float4 rw2 = *(const float4*)&W1[(size_t)(640 + 2) * NH + lane * 4];
    float4 rw3 = *(const float4*)&W1[(size_t)(640 + 3) * NH + lane * 4];
    float4 rw4 = *(const float4*)&W1[(size_t)(640 + 4) * NH + lane * 4];
    float4 rw5 = *(const float4*)&W1[(size_t)(640 + 5) * NH + lane * 4];

    float ci0 = centers[(size_t)row * 3 + 0];
    float ci1 = centers[(size_t)row * 3 + 1];
    float ci2 = centers[(size_t)row * 3 + 2];
    float si0 = sizes[(size_t)row * 3 + 0];
    float si1 = sizes[(size_t)row * 3 + 1];
    float si2 = sizes[(size_t)row * 3 + 2];

    int jn[NK];
    float sc[NK];
#pragma unroll
    for (int k = 0; k < NK; ++k) {
        int j = idx[(size_t)row * NK + k];
        jn[k] = j;
        size_t jr = (size_t)b * NN + j;
        float4 pn = Pv[jr * 128 + 64 + lane];            // projN[j]
        float rp0 = (ci0 - centers[jr * 3 + 0]) * (1.0f / 5.0f);
        float rp1 = (ci1 - centers[jr * 3 + 1]) * (1.0f / 5.0f);
        float rp2 = (ci2 - centers[jr * 3 + 2]) * (1.0f / 5.0f);
        float rs0 = (si0 - sizes[jr * 3 + 0]) * 0.5f;
        float rs1 = (si1 - sizes[jr * 3 + 1]) * 0.5f;
        float rs2 = (si2 - sizes[jr * 3 + 2]) * 0.5f;
        float hx = base.x + pn.x + rp0 * rw0.x + rp1 * rw1.x + rp2 * rw2.x
                 + rs0 * rw3.x + rs1 * rw4.x + rs2 * rw5.x;
        float hy = base.y + pn.y + rp0 * rw0.y + rp1 * rw1.y + rp2 * rw2.y
                 + rs0 * rw3.y + rs1 * rw4.y + rs2 * rw5.y;
        float hz = base.z + pn.z + rp0 * rw0.z + rp1 * rw1.z + rp2 * rw2.z
                 + rs0 * rw3.z + rs1 * rw4.z + rs2 * rw5.z;
        float hw = base.w + pn.w + rp0 * rw0.w + rp1 * rw1.w + rp2 * rw2.w
                 + rs0 * rw3.w + rs1 * rw4.w + rs2 * rw5.w;
        hx = fmaxf(hx, 0.f); hy = fmaxf(hy, 0.f);
        hz = fmaxf(hz, 0.f); hw = fmaxf(hw, 0.f);
        float part = hx * w2v.x + hy * w2v.y + hz * w2v.z + hw * w2v.w;
#pragma unroll
        for (int off = 32; off > 0; off >>= 1)
            part += __shfl_xor(part, off);
        sc[k] = part + b2v;
    }

    // softmax over k (all lanes compute identically)
    float mx = sc[0];
#pragma unroll
    for (int k = 1; k < NK; ++k) mx = fmaxf(mx, sc[k]);
    float wk[NK];
    float s = 0.f;
#pragma unroll
    for (int k = 0; k < NK; ++k) { wk[k] = expf(sc[k] - mx); s += wk[k]; }
    float inv = 1.f / s;
#pragma unroll
    for (int k = 0; k < NK; ++k) wk[k] *= inv;

    if (lane == 0) {
#pragma unroll
        for (int k = 0; k < NK; ++k)
            weights[(size_t)row * NK + k] = wk[k];
    }

    // context + residual: each lane handles d = q*64 + lane
    size_t fbase = (size_t)row * ND;
#pragma unroll
    for (int q = 0; q < 5; ++q) {
        int d = q * 64 + lane;
        float v = feats[fbase + d];
#pragma unroll
        for (int k = 0; k < NK; ++k)
            v += wk[k] * feats[((size_t)b * NN + jn[k]) * ND + d];
        enhanced[fbase + d] = v;
    }
}

extern "C" void kernel_launch(void* const* d_in, const int* in_sizes, int n_in,
                              void* d_out, int out_size, void* d_ws, size_t ws_size,
                              hipStream_t stream) {
    const float* feats   = (const float*)d_in[0];
    const float* lang    = (const float*)d_in[1];
    const float* centers = (const float*)d_in[2];
    const float* sizes   = (const float*)d_in[3];
    // d_in[4] = object_mask: all-true in this problem, ignored
    const float* W1 = (const float*)d_in[5];
    const float* b1 = (const float*)d_in[6];
    const float* W2 = (const float*)d_in[7];
    const float* b2 = (const float*)d_in[8];

    float* out = (float*)d_out;
    float* enhanced = out;                                     // [16,1024,320]
    float* weights  = out + (size_t)NB * NN * ND;              // [16,1024,5]
    float* idx_f    = weights + (size_t)NB * NN * NK;          // [16,1024,5] as float

    char* ws = (char*)d_ws;
    float* P     = (float*)ws;                                 // 16384*512*4 = 33554432 B
    int*   idx_i = (int*)(ws + 33554432);                      // 81920*4 = 327680 B
    float* LP    = (float*)(ws + 33554432 + 327680);           // 16*256*4 = 16384 B

    knn_kernel<<<dim3(4, 16), 256, 0, stream>>>(centers, idx_i, idx_f);
    proj_gemm_kernel<<<dim3(256, 8), 256, 0, stream>>>(feats, W1, P);
    langproj_kernel<<<dim3(16), 256, 0, stream>>>(lang, W1, b1, LP);
    score_kernel<<<dim3(4096), 256, 0, stream>>>(feats, centers, sizes, P, LP, W1,
                                                 W2, b2, idx_i, enhanced, weights);
}

// Round 2
// 141.904 us; speedup vs baseline: 2.0111x; 2.0111x over previous
//
#include <hip/hip_runtime.h>
#include <math.h>

#define NB 16
#define NN 1024
#define ND 320
#define NL 256
#define NH 256
#define NK 5

// ---------------- KNN v2: one wave per query -------------------------------
// Each lane scans 16 candidates keeping a sorted local top-5; then 5 rounds of
// wave-wide (dist,idx) min-reduction + pop merge the 64 local lists.
__global__ __launch_bounds__(256) void knn_kernel(const float* __restrict__ centers,
                                                  int* __restrict__ idx_i,
                                                  float* __restrict__ idx_f) {
    int wave = threadIdx.x >> 6;
    int lane = threadIdx.x & 63;
    int row = blockIdx.x * 4 + wave;    // b*NN + i
    int b = row >> 10;
    int i = row & (NN - 1);
    const float* cb = centers + (size_t)b * NN * 3;
    float px = cb[(size_t)i * 3 + 0];
    float py = cb[(size_t)i * 3 + 1];
    float pz = cb[(size_t)i * 3 + 2];

    float d0 = INFINITY, d1 = INFINITY, d2 = INFINITY, d3 = INFINITY, d4 = INFINITY;
    int i0 = -1, i1 = -1, i2 = -1, i3 = -1, i4 = -1;
#pragma unroll
    for (int t = 0; t < 16; ++t) {
        int j = t * 64 + lane;
        float dx = px - cb[(size_t)j * 3 + 0];
        float dy = py - cb[(size_t)j * 3 + 1];
        float dz = pz - cb[(size_t)j * 3 + 2];
        float d = dx * dx + dy * dy + dz * dz;
        // strict <: within a lane, j increases, so equal-dist keeps earlier j
        if ((j != i) && (d < d4)) {
            if (d < d3) {
                d4 = d3; i4 = i3;
                if (d < d2) {
                    d3 = d2; i3 = i2;
                    if (d < d1) {
                        d2 = d1; i2 = i1;
                        if (d < d0) {
                            d1 = d0; i1 = i0; d0 = d; i0 = j;
                        } else { d1 = d; i1 = j; }
                    } else { d2 = d; i2 = j; }
                } else { d3 = d; i3 = j; }
            } else { d4 = d; i4 = j; }
        }
    }

    // 5-round global merge: find wave-min (dist, idx) among lane heads, pop winner
    int r0, r1, r2, r3, r4;
#pragma unroll
    for (int k = 0; k < NK; ++k) {
        float md = d0;
        int mj = i0;
#pragma unroll
        for (int off = 32; off > 0; off >>= 1) {
            float od = __shfl_xor(md, off);
            int oj = __shfl_xor(mj, off);
            // tie-break by smaller index (unsigned: -1 pad sorts last)
            bool take = (od < md) || ((od == md) && ((unsigned)oj < (unsigned)mj));
            md = take ? od : md;
            mj = take ? oj : mj;
        }
        if (k == 0) r0 = mj;
        else if (k == 1) r1 = mj;
        else if (k == 2) r2 = mj;
        else if (k == 3) r3 = mj;
        else r4 = mj;
        if (i0 == mj) {  // exactly one lane holds this j at its head
            d0 = d1; i0 = i1; d1 = d2; i1 = i2; d2 = d3; i2 = i3;
            d3 = d4; i3 = i4; d4 = INFINITY; i4 = -1;
        }
    }

    if (lane == 0) {
        size_t base = (size_t)row * NK;
        idx_i[base + 0] = r0; idx_i[base + 1] = r1; idx_i[base + 2] = r2;
        idx_i[base + 3] = r3; idx_i[base + 4] = r4;
        idx_f[base + 0] = (float)r0; idx_f[base + 1] = (float)r1;
        idx_f[base + 2] = (float)r2; idx_f[base + 3] = (float)r3;
        idx_f[base + 4] = (float)r4;
    }
}

// ---------------- language projection: LP[b][h] = b1[h] + lang[b] @ W1[646:902] ----
__global__ __launch_bounds__(256) void langproj_kernel(const float* __restrict__ lang,
                                                       const float* __restrict__ W1,
                                                       const float* __restrict__ b1,
                                                       float* __restrict__ LP) {
    int b = blockIdx.x;
    int h = threadIdx.x;
    float acc = b1[h];
    const float* lb = lang + (size_t)b * NL;
    for (int l = 0; l < NL; ++l)
        acc = fmaf(lb[l], W1[(size_t)(646 + l) * NH + h], acc);
    LP[(size_t)b * NH + h] = acc;
}

// ---------------- P = feats[16384x320] @ W1cols -> [16384 x 512] ----------
// P[m][0:256]   = feat[m] @ W1[0:320]    (projF)
// P[m][256:512] = feat[m] @ W1[320:640]  (projN)
__global__ __launch_bounds__(256) void proj_gemm_kernel(const float* __restrict__ A,
                                                        const float* __restrict__ W1,
                                                        float* __restrict__ P) {
    __shared__ float As[32][68];  // [k][m], padded: row base 272B -> 16B aligned
    __shared__ float Bs[32][68];  // [k][n]
    int m0 = blockIdx.x * 64;
    int n0 = blockIdx.y * 64;
    int rowbase = (n0 < 256) ? 0 : 320;
    int colbase = n0 & 255;
    int t = threadIdx.x;
    int tx = t & 15, ty = t >> 4;
    float acc[4][4] = {{0.f}};
    for (int k0 = 0; k0 < ND; k0 += 32) {
#pragma unroll
        for (int it = 0; it < 8; ++it) {
            int li = it * 256 + t;
            int r = li >> 5, c = li & 31;
            As[c][r] = A[(size_t)(m0 + r) * ND + k0 + c];
        }
#pragma unroll
        for (int it = 0; it < 8; ++it) {
            int li = it * 256 + t;
            int r = li >> 6, c = li & 63;
            Bs[r][c] = W1[(size_t)(rowbase + k0 + r) * NH + colbase + c];
        }
        __syncthreads();
#pragma unroll
        for (int kk = 0; kk < 32; ++kk) {
            float4 a = *(const float4*)&As[kk][ty * 4];
            float4 bv = *(const float4*)&Bs[kk][tx * 4];
            float av[4] = {a.x, a.y, a.z, a.w};
            float bb[4] = {bv.x, bv.y, bv.z, bv.w};
#pragma unroll
            for (int i2 = 0; i2 < 4; ++i2)
#pragma unroll
                for (int j2 = 0; j2 < 4; ++j2)
                    acc[i2][j2] = fmaf(av[i2], bb[j2], acc[i2][j2]);
        }
        __syncthreads();
    }
#pragma unroll
    for (int i2 = 0; i2 < 4; ++i2) {
        float4 o = make_float4(acc[i2][0], acc[i2][1], acc[i2][2], acc[i2][3]);
        *(float4*)&P[(size_t)(m0 + ty * 4 + i2) * 512 + n0 + tx * 4] = o;
    }
}

// ---------------- score + softmax + context + residual -------------------
// one wave (64 lanes) per (b, i); 4 waves per block
__global__ __launch_bounds__(256) void score_kernel(const float* __restrict__ feats,
                                                    const float* __restrict__ centers,
                                                    const float* __restrict__ sizes,
                                                    const float* __restrict__ P,
                                                    const float* __restrict__ LP,
                                                    const float* __restrict__ W1,
                                                    const float* __restrict__ W2,
                                                    const float* __restrict__ b2,
                                                    const int* __restrict__ idx,
                                                    float* __restrict__ enhanced,
                                                    float* __restrict__ weights) {
    int wave = threadIdx.x >> 6;
    int lane = threadIdx.x & 63;
    int row = blockIdx.x * 4 + wave;     // b*NN + i
    int b = row >> 10;

    const float4* Pv = (const float4*)P;
    float4 pf = Pv[(size_t)row * 128 + lane];            // projF[i], 4 h-dims per lane
    float4 lp = ((const float4*)LP)[(size_t)b * 64 + lane];
    float4 base = make_float4(pf.x + lp.x, pf.y + lp.y, pf.z + lp.z, pf.w + lp.w);
    float4 w2v = ((const float4*)W2)[lane];
    float b2v = b2[0];
    float4 rw0 = *(const float4*)&W1[(size_t)(640 + 0) * NH + lane * 4];
    float4 rw1 = *(const float4*)&W1[(size_t)(640 + 1) * NH + lane * 4];
    float4 rw2 = *(const float4*)&W1[(size_t)(640 + 2) * NH + lane * 4];
    float4 rw3 = *(const float4*)&W1[(size_t)(640 + 3) * NH + lane * 4];
    float4 rw4 = *(const float4*)&W1[(size_t)(640 + 4) * NH + lane * 4];
    float4 rw5 = *(const float4*)&W1[(size_t)(640 + 5) * NH + lane * 4];

    float ci0 = centers[(size_t)row * 3 + 0];
    float ci1 = centers[(size_t)row * 3 + 1];
    float ci2 = centers[(size_t)row * 3 + 2];
    float si0 = sizes[(size_t)row * 3 + 0];
    float si1 = sizes[(size_t)row * 3 + 1];
    float si2 = sizes[(size_t)row * 3 + 2];

    int jn[NK];
    float sc[NK];
#pragma unroll
    for (int k = 0; k < NK; ++k) {
        int j = idx[(size_t)row * NK + k];
        jn[k] = j;
        size_t jr = (size_t)b * NN + j;
        float4 pn = Pv[jr * 128 + 64 + lane];            // projN[j]
        float rp0 = (ci0 - centers[jr * 3 + 0]) * (1.0f / 5.0f);
        float rp1 = (ci1 - centers[jr * 3 + 1]) * (1.0f / 5.0f);
        float rp2 = (ci2 - centers[jr * 3 + 2]) * (1.0f / 5.0f);
        float rs0 = (si0 - sizes[jr * 3 + 0]) * 0.5f;
        float rs1 = (si1 - sizes[jr * 3 + 1]) * 0.5f;
        float rs2 = (si2 - sizes[jr * 3 + 2]) * 0.5f;
        float hx = base.x + pn.x + rp0 * rw0.x + rp1 * rw1.x + rp2 * rw2.x
                 + rs0 * rw3.x + rs1 * rw4.x + rs2 * rw5.x;
        float hy = base.y + pn.y + rp0 * rw0.y + rp1 * rw1.y + rp2 * rw2.y
                 + rs0 * rw3.y + rs1 * rw4.y + rs2 * rw5.y;
        float hz = base.z + pn.z + rp0 * rw0.z + rp1 * rw1.z + rp2 * rw2.z
                 + rs0 * rw3.z + rs1 * rw4.z + rs2 * rw5.z;
        float hw = base.w + pn.w + rp0 * rw0.w + rp1 * rw1.w + rp2 * rw2.w
                 + rs0 * rw3.w + rs1 * rw4.w + rs2 * rw5.w;
        hx = fmaxf(hx, 0.f); hy = fmaxf(hy, 0.f);
        hz = fmaxf(hz, 0.f); hw = fmaxf(hw, 0.f);
        float part = hx * w2v.x + hy * w2v.y + hz * w2v.z + hw * w2v.w;
#pragma unroll
        for (int off = 32; off > 0; off >>= 1)
            part += __shfl_xor(part, off);
        sc[k] = part + b2v;
    }

    // softmax over k (all lanes compute identically)
    float mx = sc[0];
#pragma unroll
    for (int k = 1; k < NK; ++k) mx = fmaxf(mx, sc[k]);
    float wk[NK];
    float s = 0.f;
#pragma unroll
    for (int k = 0; k < NK; ++k) { wk[k] = expf(sc[k] - mx); s += wk[k]; }
    float inv = 1.f / s;
#pragma unroll
    for (int k = 0; k < NK; ++k) wk[k] *= inv;

    if (lane == 0) {
#pragma unroll
        for (int k = 0; k < NK; ++k)
            weights[(size_t)row * NK + k] = wk[k];
    }

    // context + residual: each lane handles d = q*64 + lane
    size_t fbase = (size_t)row * ND;
#pragma unroll
    for (int q = 0; q < 5; ++q) {
        int d = q * 64 + lane;
        float v = feats[fbase + d];
#pragma unroll
        for (int k = 0; k < NK; ++k)
            v += wk[k] * feats[((size_t)b * NN + jn[k]) * ND + d];
        enhanced[fbase + d] = v;
    }
}

extern "C" void kernel_launch(void* const* d_in, const int* in_sizes, int n_in,
                              void* d_out, int out_size, void* d_ws, size_t ws_size,
                              hipStream_t stream) {
    const float* feats   = (const float*)d_in[0];
    const float* lang    = (const float*)d_in[1];
    const float* centers = (const float*)d_in[2];
    const float* sizes   = (const float*)d_in[3];
    // d_in[4] = object_mask: all-true in this problem, ignored
    const float* W1 = (const float*)d_in[5];
    const float* b1 = (const float*)d_in[6];
    const float* W2 = (const float*)d_in[7];
    const float* b2 = (const float*)d_in[8];

    float* out = (float*)d_out;
    float* enhanced = out;                                     // [16,1024,320]
    float* weights  = out + (size_t)NB * NN * ND;              // [16,1024,5]
    float* idx_f    = weights + (size_t)NB * NN * NK;          // [16,1024,5] as float

    char* ws = (char*)d_ws;
    float* P     = (float*)ws;                                 // 16384*512*4 = 33554432 B
    int*   idx_i = (int*)(ws + 33554432);                      // 81920*4 = 327680 B
    float* LP    = (float*)(ws + 33554432 + 327680);           // 16*256*4 = 16384 B

    knn_kernel<<<dim3(4096), 256, 0, stream>>>(centers, idx_i, idx_f);
    proj_gemm_kernel<<<dim3(256, 8), 256, 0, stream>>>(feats, W1, P);
    langproj_kernel<<<dim3(16), 256, 0, stream>>>(lang, W1, b1, LP);
    score_kernel<<<dim3(4096), 256, 0, stream>>>(feats, centers, sizes, P, LP, W1,
                                                 W2, b2, idx_i, enhanced, weights);
}

// Round 3
// 84.190 us; speedup vs baseline: 3.3897x; 1.6855x over previous
//
#include <hip/hip_runtime.h>
#include <math.h>

#define NB 16
#define NN 1024
#define ND 320
#define NL 256
#define NH 256
#define NK 5

typedef short bf16x8 __attribute__((ext_vector_type(8)));
typedef float f32x4 __attribute__((ext_vector_type(4)));

__device__ inline ushort f2bf(float f) {
    unsigned u = __float_as_uint(f);
    u += 0x7fff + ((u >> 16) & 1);   // RNE (inputs are finite, no NaN handling)
    return (ushort)(u >> 16);
}
__device__ inline float bf2f(ushort u) {
    return __uint_as_float(((unsigned)u) << 16);
}

// ---------------- KNN: one wave per query ----------------------------------
__global__ __launch_bounds__(256) void knn_kernel(const float* __restrict__ centers,
                                                  int* __restrict__ idx_i,
                                                  float* __restrict__ idx_f) {
    int wave = threadIdx.x >> 6;
    int lane = threadIdx.x & 63;
    int row = blockIdx.x * 4 + wave;    // b*NN + i
    int b = row >> 10;
    int i = row & (NN - 1);
    const float* cb = centers + (size_t)b * NN * 3;
    float px = cb[(size_t)i * 3 + 0];
    float py = cb[(size_t)i * 3 + 1];
    float pz = cb[(size_t)i * 3 + 2];

    float d0 = INFINITY, d1 = INFINITY, d2 = INFINITY, d3 = INFINITY, d4 = INFINITY;
    int i0 = -1, i1 = -1, i2 = -1, i3 = -1, i4 = -1;
#pragma unroll
    for (int t = 0; t < 16; ++t) {
        int j = t * 64 + lane;
        float dx = px - cb[(size_t)j * 3 + 0];
        float dy = py - cb[(size_t)j * 3 + 1];
        float dz = pz - cb[(size_t)j * 3 + 2];
        float d = dx * dx + dy * dy + dz * dz;
        if ((j != i) && (d < d4)) {
            if (d < d3) {
                d4 = d3; i4 = i3;
                if (d < d2) {
                    d3 = d2; i3 = i2;
                    if (d < d1) {
                        d2 = d1; i2 = i1;
                        if (d < d0) {
                            d1 = d0; i1 = i0; d0 = d; i0 = j;
                        } else { d1 = d; i1 = j; }
                    } else { d2 = d; i2 = j; }
                } else { d3 = d; i3 = j; }
            } else { d4 = d; i4 = j; }
        }
    }

    int r0, r1, r2, r3, r4;
#pragma unroll
    for (int k = 0; k < NK; ++k) {
        float md = d0;
        int mj = i0;
#pragma unroll
        for (int off = 32; off > 0; off >>= 1) {
            float od = __shfl_xor(md, off);
            int oj = __shfl_xor(mj, off);
            bool take = (od < md) || ((od == md) && ((unsigned)oj < (unsigned)mj));
            md = take ? od : md;
            mj = take ? oj : mj;
        }
        if (k == 0) r0 = mj;
        else if (k == 1) r1 = mj;
        else if (k == 2) r2 = mj;
        else if (k == 3) r3 = mj;
        else r4 = mj;
        if (i0 == mj) {
            d0 = d1; i0 = i1; d1 = d2; i1 = i2; d2 = d3; i2 = i3;
            d3 = d4; i3 = i4; d4 = INFINITY; i4 = -1;
        }
    }

    if (lane == 0) {
        size_t base = (size_t)row * NK;
        idx_i[base + 0] = r0; idx_i[base + 1] = r1; idx_i[base + 2] = r2;
        idx_i[base + 3] = r3; idx_i[base + 4] = r4;
        idx_f[base + 0] = (float)r0; idx_f[base + 1] = (float)r1;
        idx_f[base + 2] = (float)r2; idx_f[base + 3] = (float)r3;
        idx_f[base + 4] = (float)r4;
    }
}

// ---------------- convert feats -> bf16 row-major [16384][320] -------------
__global__ __launch_bounds__(256) void cvtA_kernel(const float* __restrict__ F,
                                                   ushort* __restrict__ A) {
    int id = blockIdx.x * 256 + threadIdx.x;   // 1,310,720 threads, 4 elems each
    float4 v = ((const float4*)F)[id];
    ushort4 o;
    o.x = f2bf(v.x); o.y = f2bf(v.y); o.z = f2bf(v.z); o.w = f2bf(v.w);
    ((ushort4*)A)[id] = o;
}

// ---------------- W1[0:640] -> W1T bf16 [512][320] --------------------------
// row n<256: projF col n (W1 rows 0..319); n>=256: projN col n-256 (rows 320..639)
__global__ __launch_bounds__(320) void cvtW_kernel(const float* __restrict__ W1,
                                                   ushort* __restrict__ W1T) {
    int n = blockIdx.x;
    int k = threadIdx.x;
    int rowbase = (n < 256) ? 0 : 320;
    int col = n & 255;
    W1T[(size_t)n * 320 + k] = f2bf(W1[(size_t)(rowbase + k) * NH + col]);
}

// ---------------- language projection (f32) --------------------------------
__global__ __launch_bounds__(256) void langproj_kernel(const float* __restrict__ lang,
                                                       const float* __restrict__ W1,
                                                       const float* __restrict__ b1,
                                                       float* __restrict__ LP) {
    int b = blockIdx.x;
    int h = threadIdx.x;
    float acc = b1[h];
    const float* lb = lang + (size_t)b * NL;
    for (int l = 0; l < NL; ++l)
        acc = fmaf(lb[l], W1[(size_t)(646 + l) * NH + h], acc);
    LP[(size_t)b * NH + h] = acc;
}

// ---------------- MFMA GEMM: P[16384][512] bf16 = A[16384x320] @ W1T^T ------
// 128x128 tile, BK=32, 4 waves each 64x64 (4x4 frags of 16x16x32 bf16 MFMA).
// LDS rows padded to 40 ushorts (80 B = 20 dwords): both frag-reads and staging
// writes are perfectly bank-balanced (8 touches/bank = b128 minimum).
#define LDP 40
__global__ __launch_bounds__(256) void mfma_gemm_kernel(const ushort* __restrict__ A,
                                                        const ushort* __restrict__ BT,
                                                        ushort* __restrict__ P) {
    __shared__ ushort Als[128 * LDP];
    __shared__ ushort Bls[128 * LDP];
    int t = threadIdx.x;
    int lane = t & 63;
    int w = t >> 6;
    int wrow = (w >> 1) * 64, wcol = (w & 1) * 64;
    int m0 = blockIdx.x * 128, n0 = blockIdx.y * 128;
    int lr = lane & 15;     // fragment row (A) / col (B)
    int lg = lane >> 4;     // k-group

    f32x4 zero = {0.f, 0.f, 0.f, 0.f};
    f32x4 acc[4][4];
#pragma unroll
    for (int i = 0; i < 4; ++i)
#pragma unroll
        for (int j = 0; j < 4; ++j) acc[i][j] = zero;

    for (int ks = 0; ks < 10; ++ks) {
        int k0 = ks * 32;
#pragma unroll
        for (int it = 0; it < 2; ++it) {
            int c = it * 256 + t;
            int r = c >> 2, q = c & 3;
            *(int4*)&Als[r * LDP + q * 8] =
                *(const int4*)&A[(size_t)(m0 + r) * 320 + k0 + q * 8];
            *(int4*)&Bls[r * LDP + q * 8] =
                *(const int4*)&BT[(size_t)(n0 + r) * 320 + k0 + q * 8];
        }
        __syncthreads();
        bf16x8 af[4], bfr[4];
#pragma unroll
        for (int i = 0; i < 4; ++i) {
            af[i]  = *(bf16x8*)&Als[(wrow + i * 16 + lr) * LDP + lg * 8];
            bfr[i] = *(bf16x8*)&Bls[(wcol + i * 16 + lr) * LDP + lg * 8];
        }
#pragma unroll
        for (int i = 0; i < 4; ++i)
#pragma unroll
            for (int j = 0; j < 4; ++j)
                acc[i][j] = __builtin_amdgcn_mfma_f32_16x16x32_bf16(af[i], bfr[j],
                                                                    acc[i][j], 0, 0, 0);
        __syncthreads();
    }

#pragma unroll
    for (int i = 0; i < 4; ++i) {
#pragma unroll
        for (int j = 0; j < 4; ++j) {
            int col = n0 + wcol + j * 16 + lr;
#pragma unroll
            for (int e = 0; e < 4; ++e) {
                int row = m0 + wrow + i * 16 + (lane >> 4) * 4 + e;
                P[(size_t)row * 512 + col] = f2bf(acc[i][j][e]);
            }
        }
    }
}

// ---------------- score + softmax + context + residual ---------------------
__global__ __launch_bounds__(256) void score_kernel(const float* __restrict__ feats,
                                                    const float* __restrict__ centers,
                                                    const float* __restrict__ sizes,
                                                    const ushort* __restrict__ P,
                                                    const float* __restrict__ LP,
                                                    const float* __restrict__ W1,
                                                    const float* __restrict__ W2,
                                                    const float* __restrict__ b2,
                                                    const int* __restrict__ idx,
                                                    float* __restrict__ enhanced,
                                                    float* __restrict__ weights) {
    int wave = threadIdx.x >> 6;
    int lane = threadIdx.x & 63;
    int row = blockIdx.x * 4 + wave;     // b*NN + i
    int b = row >> 10;

    ushort4 pfu = *(const ushort4*)&P[(size_t)row * 512 + lane * 4];
    float4 lp = ((const float4*)LP)[(size_t)b * 64 + lane];
    float4 base = make_float4(bf2f(pfu.x) + lp.x, bf2f(pfu.y) + lp.y,
                              bf2f(pfu.z) + lp.z, bf2f(pfu.w) + lp.w);
    float4 w2v = ((const float4*)W2)[lane];
    float b2v = b2[0];
    float4 rw0 = *(const float4*)&W1[(size_t)(640 + 0) * NH + lane * 4];
    float4 rw1 = *(const float4*)&W1[(size_t)(640 + 1) * NH + lane * 4];
    float4 rw2 = *(const float4*)&W1[(size_t)(640 + 2) * NH + lane * 4];
    float4 rw3 = *(const float4*)&W1[(size_t)(640 + 3) * NH + lane * 4];
    float4 rw4 = *(const float4*)&W1[(size_t)(640 + 4) * NH + lane * 4];
    float4 rw5 = *(const float4*)&W1[(size_t)(640 + 5) * NH + lane * 4];

    float ci0 = centers[(size_t)row * 3 + 0];
    float ci1 = centers[(size_t)row * 3 + 1];
    float ci2 = centers[(size_t)row * 3 + 2];
    float si0 = sizes[(size_t)row * 3 + 0];
    float si1 = sizes[(size_t)row * 3 + 1];
    float si2 = sizes[(size_t)row * 3 + 2];

    int jn[NK];
    float sc[NK];
#pragma unroll
    for (int k = 0; k < NK; ++k) {
        int j = idx[(size_t)row * NK + k];
        jn[k] = j;
        size_t jr = (size_t)b * NN + j;
        ushort4 pnu = *(const ushort4*)&P[jr * 512 + 256 + lane * 4];
        float rp0 = (ci0 - centers[jr * 3 + 0]) * (1.0f / 5.0f);
        float rp1 = (ci1 - centers[jr * 3 + 1]) * (1.0f / 5.0f);
        float rp2 = (ci2 - centers[jr * 3 + 2]) * (1.0f / 5.0f);
        float rs0 = (si0 - sizes[jr * 3 + 0]) * 0.5f;
        float rs1 = (si1 - sizes[jr * 3 + 1]) * 0.5f;
        float rs2 = (si2 - sizes[jr * 3 + 2]) * 0.5f;
        float hx = base.x + bf2f(pnu.x) + rp0 * rw0.x + rp1 * rw1.x + rp2 * rw2.x
                 + rs0 * rw3.x + rs1 * rw4.x + rs2 * rw5.x;
        float hy = base.y + bf2f(pnu.y) + rp0 * rw0.y + rp1 * rw1.y + rp2 * rw2.y
                 + rs0 * rw3.y + rs1 * rw4.y + rs2 * rw5.y;
        float hz = base.z + bf2f(pnu.z) + rp0 * rw0.z + rp1 * rw1.z + rp2 * rw2.z
                 + rs0 * rw3.z + rs1 * rw4.z + rs2 * rw5.z;
        float hw = base.w + bf2f(pnu.w) + rp0 * rw0.w + rp1 * rw1.w + rp2 * rw2.w
                 + rs0 * rw3.w + rs1 * rw4.w + rs2 * rw5.w;
        hx = fmaxf(hx, 0.f); hy = fmaxf(hy, 0.f);
        hz = fmaxf(hz, 0.f); hw = fmaxf(hw, 0.f);
        float part = hx * w2v.x + hy * w2v.y + hz * w2v.z + hw * w2v.w;
#pragma unroll
        for (int off = 32; off > 0; off >>= 1)
            part += __shfl_xor(part, off);
        sc[k] = part + b2v;
    }

    float mx = sc[0];
#pragma unroll
    for (int k = 1; k < NK; ++k) mx = fmaxf(mx, sc[k]);
    float wk[NK];
    float s = 0.f;
#pragma unroll
    for (int k = 0; k < NK; ++k) { wk[k] = expf(sc[k] - mx); s += wk[k]; }
    float inv = 1.f / s;
#pragma unroll
    for (int k = 0; k < NK; ++k) wk[k] *= inv;

    if (lane == 0) {
#pragma unroll
        for (int k = 0; k < NK; ++k)
            weights[(size_t)row * NK + k] = wk[k];
    }

    size_t fbase = (size_t)row * ND;
#pragma unroll
    for (int q = 0; q < 5; ++q) {
        int d = q * 64 + lane;
        float v = feats[fbase + d];
#pragma unroll
        for (int k = 0; k < NK; ++k)
            v += wk[k] * feats[((size_t)b * NN + jn[k]) * ND + d];
        enhanced[fbase + d] = v;
    }
}

extern "C" void kernel_launch(void* const* d_in, const int* in_sizes, int n_in,
                              void* d_out, int out_size, void* d_ws, size_t ws_size,
                              hipStream_t stream) {
    const float* feats   = (const float*)d_in[0];
    const float* lang    = (const float*)d_in[1];
    const float* centers = (const float*)d_in[2];
    const float* sizes   = (const float*)d_in[3];
    // d_in[4] = object_mask: all-true, ignored
    const float* W1 = (const float*)d_in[5];
    const float* b1 = (const float*)d_in[6];
    const float* W2 = (const float*)d_in[7];
    const float* b2 = (const float*)d_in[8];

    float* out = (float*)d_out;
    float* enhanced = out;                                     // [16,1024,320]
    float* weights  = out + (size_t)NB * NN * ND;              // [16,1024,5]
    float* idx_f    = weights + (size_t)NB * NN * NK;          // [16,1024,5] as float

    char* ws = (char*)d_ws;
    ushort* P     = (ushort*)ws;                               // 16384*512*2  = 16,777,216 B
    ushort* Abf   = (ushort*)(ws + 16777216);                  // 16384*320*2  = 10,485,760 B
    ushort* W1T   = (ushort*)(ws + 16777216 + 10485760);       // 512*320*2    = 327,680 B
    int*    idx_i = (int*)(ws + 16777216 + 10485760 + 327680); // 81920*4      = 327,680 B
    float*  LP    = (float*)(ws + 16777216 + 10485760 + 327680 + 327680); // 16 KB

    knn_kernel<<<dim3(4096), 256, 0, stream>>>(centers, idx_i, idx_f);
    cvtA_kernel<<<dim3(5120), 256, 0, stream>>>(feats, Abf);
    cvtW_kernel<<<dim3(512), 320, 0, stream>>>(W1, W1T);
    langproj_kernel<<<dim3(16), 256, 0, stream>>>(lang, W1, b1, LP);
    mfma_gemm_kernel<<<dim3(128, 4), 256, 0, stream>>>(Abf, W1T, P);
    score_kernel<<<dim3(4096), 256, 0, stream>>>(feats, centers, sizes, P, LP, W1,
                                                 W2, b2, idx_i, enhanced, weights);
}

// Round 4
// 70.176 us; speedup vs baseline: 4.0665x; 1.1997x over previous
//
#include <hip/hip_runtime.h>
#include <math.h>

#define NB 16
#define NN 1024
#define ND 320
#define NL 256
#define NH 256
#define NK 5

typedef short bf16x8 __attribute__((ext_vector_type(8)));
typedef float f32x4 __attribute__((ext_vector_type(4)));

__device__ inline ushort f2bf(float f) {
    unsigned u = __float_as_uint(f);
    u += 0x7fff + ((u >> 16) & 1);   // RNE (inputs finite, no NaN handling)
    return (ushort)(u >> 16);
}
__device__ inline float bf2f(ushort u) {
    return __uint_as_float(((unsigned)u) << 16);
}

// ---------------- prep: knn (4096 blocks) + W1T convert (512) + langproj (64)
__global__ __launch_bounds__(256) void prep_kernel(const float* __restrict__ centers,
                                                   int* __restrict__ idx_i,
                                                   float* __restrict__ idx_f,
                                                   const float* __restrict__ W1,
                                                   ushort* __restrict__ W1T,
                                                   const float* __restrict__ lang,
                                                   const float* __restrict__ b1,
                                                   float* __restrict__ LP) {
    __shared__ float red[4][64];
    int bid = blockIdx.x;
    if (bid < 4096) {
        // ---- KNN: one wave per query ----
        int wave = threadIdx.x >> 6;
        int lane = threadIdx.x & 63;
        int row = bid * 4 + wave;       // b*NN + i
        int b = row >> 10;
        int i = row & (NN - 1);
        const float* cb = centers + (size_t)b * NN * 3;
        float px = cb[(size_t)i * 3 + 0];
        float py = cb[(size_t)i * 3 + 1];
        float pz = cb[(size_t)i * 3 + 2];

        float d0 = INFINITY, d1 = INFINITY, d2 = INFINITY, d3 = INFINITY, d4 = INFINITY;
        int i0 = -1, i1 = -1, i2 = -1, i3 = -1, i4 = -1;
#pragma unroll
        for (int t = 0; t < 16; ++t) {
            int j = t * 64 + lane;
            float dx = px - cb[(size_t)j * 3 + 0];
            float dy = py - cb[(size_t)j * 3 + 1];
            float dz = pz - cb[(size_t)j * 3 + 2];
            float d = dx * dx + dy * dy + dz * dz;
            if ((j != i) && (d < d4)) {
                if (d < d3) {
                    d4 = d3; i4 = i3;
                    if (d < d2) {
                        d3 = d2; i3 = i2;
                        if (d < d1) {
                            d2 = d1; i2 = i1;
                            if (d < d0) {
                                d1 = d0; i1 = i0; d0 = d; i0 = j;
                            } else { d1 = d; i1 = j; }
                        } else { d2 = d; i2 = j; }
                    } else { d3 = d; i3 = j; }
                } else { d4 = d; i4 = j; }
            }
        }

        int r0, r1, r2, r3, r4;
#pragma unroll
        for (int k = 0; k < NK; ++k) {
            float md = d0;
            int mj = i0;
#pragma unroll
            for (int off = 32; off > 0; off >>= 1) {
                float od = __shfl_xor(md, off);
                int oj = __shfl_xor(mj, off);
                bool take = (od < md) || ((od == md) && ((unsigned)oj < (unsigned)mj));
                md = take ? od : md;
                mj = take ? oj : mj;
            }
            if (k == 0) r0 = mj;
            else if (k == 1) r1 = mj;
            else if (k == 2) r2 = mj;
            else if (k == 3) r3 = mj;
            else r4 = mj;
            if (i0 == mj) {
                d0 = d1; i0 = i1; d1 = d2; i1 = i2; d2 = d3; i2 = i3;
                d3 = d4; i3 = i4; d4 = INFINITY; i4 = -1;
            }
        }

        if (lane == 0) {
            size_t base = (size_t)row * NK;
            idx_i[base + 0] = r0; idx_i[base + 1] = r1; idx_i[base + 2] = r2;
            idx_i[base + 3] = r3; idx_i[base + 4] = r4;
            idx_f[base + 0] = (float)r0; idx_f[base + 1] = (float)r1;
            idx_f[base + 2] = (float)r2; idx_f[base + 3] = (float)r3;
            idx_f[base + 4] = (float)r4;
        }
        return;
    }
    if (bid < 4608) {
        // ---- W1[0:640] -> W1T bf16 [512][320] ----
        int n = bid - 4096;
        int rowbase = (n < 256) ? 0 : 320;
        int col = n & 255;
        for (int k = threadIdx.x; k < 320; k += 256)
            W1T[(size_t)n * 320 + k] = f2bf(W1[(size_t)(rowbase + k) * NH + col]);
        return;
    }
    // ---- language projection: LP[b][h] = b1[h] + lang[b] @ W1[646:902] ----
    int id = bid - 4608;             // 0..63
    int b = id >> 2, hq = id & 3;
    int w = threadIdx.x >> 6, lane = threadIdx.x & 63;
    int h = hq * 64 + lane;
    const float* lb = lang + (size_t)b * NL;
    float acc = 0.f;
    int l0 = w * 64;
#pragma unroll 8
    for (int l = 0; l < 64; ++l)
        acc = fmaf(lb[l0 + l], W1[(size_t)(646 + l0 + l) * NH + h], acc);
    red[w][lane] = acc;
    __syncthreads();
    if (w == 0)
        LP[(size_t)b * NH + h] = b1[h] + red[0][lane] + red[1][lane]
                               + red[2][lane] + red[3][lane];
}

// ---------------- MFMA GEMM: P[16384][512] bf16 = feats @ W1T^T -------------
// A staged from f32 with inline bf16 convert; 128x128 tile, BK=32, 4 waves
// each 64x64 via 16x16x32 bf16 MFMA. LDS rows padded to 40 ushorts (80 B):
// frag b128 reads and staging writes both bank-balanced (8 touches/bank).
#define LDP 40
__global__ __launch_bounds__(256) void mfma_gemm_kernel(const float* __restrict__ A32,
                                                        const ushort* __restrict__ BT,
                                                        ushort* __restrict__ P) {
    __shared__ ushort Als[128 * LDP];
    __shared__ ushort Bls[128 * LDP];
    int t = threadIdx.x;
    int lane = t & 63;
    int w = t >> 6;
    int wrow = (w >> 1) * 64, wcol = (w & 1) * 64;
    int m0 = blockIdx.x * 128, n0 = blockIdx.y * 128;
    int lr = lane & 15;
    int lg = lane >> 4;

    f32x4 zero = {0.f, 0.f, 0.f, 0.f};
    f32x4 acc[4][4];
#pragma unroll
    for (int i = 0; i < 4; ++i)
#pragma unroll
        for (int j = 0; j < 4; ++j) acc[i][j] = zero;

    for (int ks = 0; ks < 10; ++ks) {
        int k0 = ks * 32;
#pragma unroll
        for (int it = 0; it < 2; ++it) {
            int s = it * 256 + t;
            int r = s >> 2, q = s & 3;
            const float* src = &A32[(size_t)(m0 + r) * 320 + k0 + q * 8];
            float4 v0 = *(const float4*)src;
            float4 v1 = *(const float4*)(src + 4);
            int4 pk;
            pk.x = (int)f2bf(v0.x) | ((int)f2bf(v0.y) << 16);
            pk.y = (int)f2bf(v0.z) | ((int)f2bf(v0.w) << 16);
            pk.z = (int)f2bf(v1.x) | ((int)f2bf(v1.y) << 16);
            pk.w = (int)f2bf(v1.z) | ((int)f2bf(v1.w) << 16);
            *(int4*)&Als[r * LDP + q * 8] = pk;
            *(int4*)&Bls[r * LDP + q * 8] =
                *(const int4*)&BT[(size_t)(n0 + r) * 320 + k0 + q * 8];
        }
        __syncthreads();
        bf16x8 af[4], bfr[4];
#pragma unroll
        for (int i = 0; i < 4; ++i) {
            af[i]  = *(bf16x8*)&Als[(wrow + i * 16 + lr) * LDP + lg * 8];
            bfr[i] = *(bf16x8*)&Bls[(wcol + i * 16 + lr) * LDP + lg * 8];
        }
#pragma unroll
        for (int i = 0; i < 4; ++i)
#pragma unroll
            for (int j = 0; j < 4; ++j)
                acc[i][j] = __builtin_amdgcn_mfma_f32_16x16x32_bf16(af[i], bfr[j],
                                                                    acc[i][j], 0, 0, 0);
        __syncthreads();
    }

#pragma unroll
    for (int i = 0; i < 4; ++i) {
#pragma unroll
        for (int j = 0; j < 4; ++j) {
            int col = n0 + wcol + j * 16 + lr;
#pragma unroll
            for (int e = 0; e < 4; ++e) {
                int row = m0 + wrow + i * 16 + lg * 4 + e;
                P[(size_t)row * 512 + col] = f2bf(acc[i][j][e]);
            }
        }
    }
}

// ---------------- score + softmax + context + residual ---------------------
__global__ __launch_bounds__(256) void score_kernel(const float* __restrict__ feats,
                                                    const float* __restrict__ centers,
                                                    const float* __restrict__ sizes,
                                                    const ushort* __restrict__ P,
                                                    const float* __restrict__ LP,
                                                    const float* __restrict__ W1,
                                                    const float* __restrict__ W2,
                                                    const float* __restrict__ b2,
                                                    const int* __restrict__ idx,
                                                    float* __restrict__ enhanced,
                                                    float* __restrict__ weights) {
    int wave = threadIdx.x >> 6;
    int lane = threadIdx.x & 63;
    int row = blockIdx.x * 4 + wave;     // b*NN + i
    int b = row >> 10;

    ushort4 pfu = *(const ushort4*)&P[(size_t)row * 512 + lane * 4];
    float4 lp = ((const float4*)LP)[(size_t)b * 64 + lane];
    float4 base = make_float4(bf2f(pfu.x) + lp.x, bf2f(pfu.y) + lp.y,
                              bf2f(pfu.z) + lp.z, bf2f(pfu.w) + lp.w);
    float4 w2v = ((const float4*)W2)[lane];
    float b2v = b2[0];
    float4 rw0 = *(const float4*)&W1[(size_t)(640 + 0) * NH + lane * 4];
    float4 rw1 = *(const float4*)&W1[(size_t)(640 + 1) * NH + lane * 4];
    float4 rw2 = *(const float4*)&W1[(size_t)(640 + 2) * NH + lane * 4];
    float4 rw3 = *(const float4*)&W1[(size_t)(640 + 3) * NH + lane * 4];
    float4 rw4 = *(const float4*)&W1[(size_t)(640 + 4) * NH + lane * 4];
    float4 rw5 = *(const float4*)&W1[(size_t)(640 + 5) * NH + lane * 4];

    float ci0 = centers[(size_t)row * 3 + 0];
    float ci1 = centers[(size_t)row * 3 + 1];
    float ci2 = centers[(size_t)row * 3 + 2];
    float si0 = sizes[(size_t)row * 3 + 0];
    float si1 = sizes[(size_t)row * 3 + 1];
    float si2 = sizes[(size_t)row * 3 + 2];

    int jn[NK];
    float sc[NK];
#pragma unroll
    for (int k = 0; k < NK; ++k) {
        int j = idx[(size_t)row * NK + k];
        jn[k] = j;
        size_t jr = (size_t)b * NN + j;
        ushort4 pnu = *(const ushort4*)&P[jr * 512 + 256 + lane * 4];
        float rp0 = (ci0 - centers[jr * 3 + 0]) * (1.0f / 5.0f);
        float rp1 = (ci1 - centers[jr * 3 + 1]) * (1.0f / 5.0f);
        float rp2 = (ci2 - centers[jr * 3 + 2]) * (1.0f / 5.0f);
        float rs0 = (si0 - sizes[jr * 3 + 0]) * 0.5f;
        float rs1 = (si1 - sizes[jr * 3 + 1]) * 0.5f;
        float rs2 = (si2 - sizes[jr * 3 + 2]) * 0.5f;
        float hx = base.x + bf2f(pnu.x) + rp0 * rw0.x + rp1 * rw1.x + rp2 * rw2.x
                 + rs0 * rw3.x + rs1 * rw4.x + rs2 * rw5.x;
        float hy = base.y + bf2f(pnu.y) + rp0 * rw0.y + rp1 * rw1.y + rp2 * rw2.y
                 + rs0 * rw3.y + rs1 * rw4.y + rs2 * rw5.y;
        float hz = base.z + bf2f(pnu.z) + rp0 * rw0.z + rp1 * rw1.z + rp2 * rw2.z
                 + rs0 * rw3.z + rs1 * rw4.z + rs2 * rw5.z;
        float hw = base.w + bf2f(pnu.w) + rp0 * rw0.w + rp1 * rw1.w + rp2 * rw2.w
                 + rs0 * rw3.w + rs1 * rw4.w + rs2 * rw5.w;
        hx = fmaxf(hx, 0.f); hy = fmaxf(hy, 0.f);
        hz = fmaxf(hz, 0.f); hw = fmaxf(hw, 0.f);
        float part = hx * w2v.x + hy * w2v.y + hz * w2v.z + hw * w2v.w;
#pragma unroll
        for (int off = 32; off > 0; off >>= 1)
            part += __shfl_xor(part, off);
        sc[k] = part + b2v;
    }

    float mx = sc[0];
#pragma unroll
    for (int k = 1; k < NK; ++k) mx = fmaxf(mx, sc[k]);
    float wk[NK];
    float s = 0.f;
#pragma unroll
    for (int k = 0; k < NK; ++k) { wk[k] = expf(sc[k] - mx); s += wk[k]; }
    float inv = 1.f / s;
#pragma unroll
    for (int k = 0; k < NK; ++k) wk[k] *= inv;

    if (lane == 0) {
#pragma unroll
        for (int k = 0; k < NK; ++k)
            weights[(size_t)row * NK + k] = wk[k];
    }

    size_t fbase = (size_t)row * ND;
#pragma unroll
    for (int q = 0; q < 5; ++q) {
        int d = q * 64 + lane;
        float v = feats[fbase + d];
#pragma unroll
        for (int k = 0; k < NK; ++k)
            v += wk[k] * feats[((size_t)b * NN + jn[k]) * ND + d];
        enhanced[fbase + d] = v;
    }
}

extern "C" void kernel_launch(void* const* d_in, const int* in_sizes, int n_in,
                              void* d_out, int out_size, void* d_ws, size_t ws_size,
                              hipStream_t stream) {
    const float* feats   = (const float*)d_in[0];
    const float* lang    = (const float*)d_in[1];
    const float* centers = (const float*)d_in[2];
    const float* sizes   = (const float*)d_in[3];
    // d_in[4] = object_mask: all-true, ignored
    const float* W1 = (const float*)d_in[5];
    const float* b1 = (const float*)d_in[6];
    const float* W2 = (const float*)d_in[7];
    const float* b2 = (const float*)d_in[8];

    float* out = (float*)d_out;
    float* enhanced = out;                                     // [16,1024,320]
    float* weights  = out + (size_t)NB * NN * ND;              // [16,1024,5]
    float* idx_f    = weights + (size_t)NB * NN * NK;          // [16,1024,5] as float

    char* ws = (char*)d_ws;
    ushort* P     = (ushort*)ws;                               // 16384*512*2 = 16,777,216 B
    ushort* W1T   = (ushort*)(ws + 16777216);                  // 512*320*2   = 327,680 B
    int*    idx_i = (int*)(ws + 16777216 + 327680);            // 81920*4     = 327,680 B
    float*  LP    = (float*)(ws + 16777216 + 327680 + 327680); // 16*256*4    = 16,384 B

    prep_kernel<<<dim3(4672), 256, 0, stream>>>(centers, idx_i, idx_f,
                                                W1, W1T, lang, b1, LP);
    mfma_gemm_kernel<<<dim3(128, 4), 256, 0, stream>>>(feats, W1T, P);
    score_kernel<<<dim3(4096), 256, 0, stream>>>(feats, centers, sizes, P, LP, W1,
                                                 W2, b2, idx_i, enhanced, weights);
}